// Round 1
// baseline (64.128 us; speedup 1.0000x reference)
//
#include <hip/hip_runtime.h>

#define NN 16
constexpr int BB = 32, CIN = 64, HH = 112, WW = 112;
constexpr int HWC = HH * WW;          // 12544
constexpr int COUT = 128, HW2 = 56 * 56;
constexpr int NE = 64;
constexpr int NQ = HWC / 4;           // 3136 float4 pixels per image
constexpr int BPI = 13;               // blocks per image (13*256 >= 3136)
constexpr int NOUT4 = BB * COUT * HW2 / 4;   // 3211264

// ---------------- Kernel 1: 1x1 conv over 64 ch + segment scatter ----------
__global__ __launch_bounds__(256) void k_conv_seg(
    const float* __restrict__ Bfor, const int* __restrict__ seg,
    const float* __restrict__ convw, float* __restrict__ accg)
{
    __shared__ float w[CIN];
    __shared__ float acc[8][NN][4];   // 8-way replicated to cut LDS atomic contention
    const int tid = threadIdx.x;
    const int b   = blockIdx.x / BPI;
    const int blk = blockIdx.x % BPI;

    if (tid < CIN) w[tid] = convw[tid];
    for (int i = tid; i < 8 * NN * 4; i += 256) ((float*)acc)[i] = 0.f;
    __syncthreads();

    const float* base = Bfor + (size_t)b * CIN * HWC;
    const int*   segb = seg  + (size_t)b * HWC;
    const int bank = tid & 7;

    for (int q = blk * 256 + tid; q < NQ; q += BPI * 256) {
        const int p = q * 4;
        float4 s = make_float4(0.f, 0.f, 0.f, 0.f);
        #pragma unroll 8
        for (int c = 0; c < CIN; ++c) {
            float4 v = *reinterpret_cast<const float4*>(base + (size_t)c * HWC + p);
            const float wc = w[c];
            s.x = fmaf(v.x, wc, s.x);
            s.y = fmaf(v.y, wc, s.y);
            s.z = fmaf(v.z, wc, s.z);
            s.w = fmaf(v.w, wc, s.w);
        }
        const int4 sg = *reinterpret_cast<const int4*>(segb + p);
        const float row  = (float)(p / WW);
        const float col0 = (float)(p % WW);
        atomicAdd(&acc[bank][sg.x][0], row);
        atomicAdd(&acc[bank][sg.x][1], col0);
        atomicAdd(&acc[bank][sg.x][2], s.x);
        atomicAdd(&acc[bank][sg.x][3], 1.f);
        atomicAdd(&acc[bank][sg.y][0], row);
        atomicAdd(&acc[bank][sg.y][1], col0 + 1.f);
        atomicAdd(&acc[bank][sg.y][2], s.y);
        atomicAdd(&acc[bank][sg.y][3], 1.f);
        atomicAdd(&acc[bank][sg.z][0], row);
        atomicAdd(&acc[bank][sg.z][1], col0 + 2.f);
        atomicAdd(&acc[bank][sg.z][2], s.z);
        atomicAdd(&acc[bank][sg.z][3], 1.f);
        atomicAdd(&acc[bank][sg.w][0], row);
        atomicAdd(&acc[bank][sg.w][1], col0 + 3.f);
        atomicAdd(&acc[bank][sg.w][2], s.w);
        atomicAdd(&acc[bank][sg.w][3], 1.f);
    }
    __syncthreads();

    if (tid < NN * 4) {
        const int node = tid >> 2, st = tid & 3;
        float v = 0.f;
        #pragma unroll
        for (int k = 0; k < 8; ++k) v += acc[k][node][st];
        atomicAdd(&accg[(b * NN + node) * 4 + st], v);
    }
}

// ---------------- Kernel 2: features + adjacency + 2 graph convs + FC ------
__global__ __launch_bounds__(128) void k_graph(
    const float* __restrict__ accg, const int* __restrict__ src,
    const int* __restrict__ dst,  const float* __restrict__ convb,
    const float* __restrict__ W1, const float* __restrict__ b1,
    const float* __restrict__ W2, const float* __restrict__ b2,
    const float* __restrict__ fcw, const float* __restrict__ fcb,
    float* __restrict__ G)
{
    const int b = blockIdx.x, tid = threadIdx.x;
    __shared__ float X[NN][4];
    __shared__ float A[NN][NN];
    __shared__ float nrm[NN];
    __shared__ float h1s[NN][32];
    __shared__ float agg[NN][32];

    if (tid < NN) {
        const float* a = accg + (b * NN + tid) * 4;
        const float cnt = a[3];
        const float cs  = fmaxf(cnt, 1.f);
        X[tid][0] = a[0] / cs;
        X[tid][1] = a[1] / cs;
        X[tid][2] = (a[2] + cnt * convb[0]) / cs;  // conv bias folded in here
        X[tid][3] = cnt;
    }
    for (int i = tid; i < NN * NN; i += 128) ((float*)A)[i] = 0.f;
    __syncthreads();

    // normalize feature cols 2,3 across nodes (mean, std ddof=1)
    if (tid < 2) {
        const int c = 2 + tid;
        float mu = 0.f;
        for (int i = 0; i < NN; ++i) mu += X[i][c];
        mu *= (1.f / NN);
        float var = 0.f;
        for (int i = 0; i < NN; ++i) { const float d = X[i][c] - mu; var = fmaf(d, d, var); }
        var *= (1.f / (NN - 1));
        const float inv = 1.f / (sqrtf(var) + 1.f);
        for (int i = 0; i < NN; ++i) X[i][c] = (X[i][c] - mu) * inv;
    }
    // build adjacency (idempotent set-to-1, concurrent same-value writes fine)
    if (tid >= 64 && tid < 64 + NE) {
        const int e = tid - 64;
        const int s = src[b * NE + e], d = dst[b * NE + e];
        A[s][d] = 1.f;
        A[d][s] = 1.f;
    }
    __syncthreads();

    if (tid < NN) {
        float rs = 0.f;
        for (int j = 0; j < NN; ++j) rs += A[tid][j];
        nrm[tid] = 1.f / sqrtf(fmaxf(rs, 1.f));
    }
    __syncthreads();

    // agg1[i][k] = sum_j A[i][j]*nrm[j]*X[j][k]  (16x4), stored in agg[][0..3]
    if (tid < NN * 4) {
        const int i = tid >> 2, k = tid & 3;
        float s = 0.f;
        for (int j = 0; j < NN; ++j) s = fmaf(A[i][j] * nrm[j], X[j][k], s);
        agg[i][k] = s;
    }
    __syncthreads();

    // h1[i][f] = relu(nrm[i]*(agg1[i]·W1[:,f]) + b1[f])   (16x32)
    for (int t = tid; t < NN * 32; t += 128) {
        const int i = t >> 5, f = t & 31;
        float s = 0.f;
        #pragma unroll
        for (int k = 0; k < 4; ++k) s = fmaf(agg[i][k], W1[k * 32 + f], s);
        h1s[i][f] = fmaxf(fmaf(nrm[i], s, b1[f]), 0.f);
    }
    __syncthreads();

    // agg2[i][k] = sum_j A[i][j]*nrm[j]*h1[j][k]  (16x32) — overwrite agg
    for (int t = tid; t < NN * 32; t += 128) {
        const int i = t >> 5, k = t & 31;
        float s = 0.f;
        for (int j = 0; j < NN; ++j) s = fmaf(A[i][j] * nrm[j], h1s[j][k], s);
        agg[i][k] = s;
    }
    __syncthreads();

    // h2[i][f] = relu(nrm[i]*(agg2[i]·W2[:,f]) + b2[f]); G[f] = sum_i fcw[i]*h2[i][f] + fcb
    {
        const int f = tid;                    // 128 threads == COUT
        float g = fcb[0];
        const float bf = b2[f];
        for (int i = 0; i < NN; ++i) {
            float s = 0.f;
            #pragma unroll 8
            for (int k = 0; k < 32; ++k) s = fmaf(agg[i][k], W2[k * COUT + f], s);
            const float h2 = fmaxf(fmaf(nrm[i], s, bf), 0.f);
            g = fmaf(fcw[i], h2, g);
        }
        G[b * COUT + f] = g;
    }
}

// ---------------- Kernel 3: out[b,c,h,w] = G[b,c] * B_fon[b,c,h,w] ---------
__global__ __launch_bounds__(256) void k_scale(
    const float* __restrict__ Bfon, const float* __restrict__ G,
    float* __restrict__ out)
{
    const int i = blockIdx.x * 256 + threadIdx.x;
    if (i >= NOUT4) return;
    const float4 v = reinterpret_cast<const float4*>(Bfon)[i];
    const float g = G[i / (HW2 / 4)];    // 784 float4s per (b,c) plane
    reinterpret_cast<float4*>(out)[i] = make_float4(v.x * g, v.y * g, v.z * g, v.w * g);
}

extern "C" void kernel_launch(void* const* d_in, const int* in_sizes, int n_in,
                              void* d_out, int out_size, void* d_ws, size_t ws_size,
                              hipStream_t stream)
{
    const float* Bfor  = (const float*)d_in[0];
    const float* Bfon  = (const float*)d_in[1];
    const int*   seg   = (const int*)d_in[2];
    const int*   src   = (const int*)d_in[3];
    const int*   dst   = (const int*)d_in[4];
    const float* convw = (const float*)d_in[5];
    const float* convb = (const float*)d_in[6];
    const float* W1    = (const float*)d_in[7];
    const float* b1    = (const float*)d_in[8];
    const float* W2    = (const float*)d_in[9];
    const float* b2    = (const float*)d_in[10];
    const float* fcw   = (const float*)d_in[11];
    const float* fcb   = (const float*)d_in[12];

    float* acc = (float*)d_ws;            // B*16*4 floats
    float* G   = acc + BB * NN * 4;       // B*128 floats
    float* out = (float*)d_out;

    hipMemsetAsync(acc, 0, BB * NN * 4 * sizeof(float), stream);
    k_conv_seg<<<BB * BPI, 256, 0, stream>>>(Bfor, seg, convw, acc);
    k_graph<<<BB, 128, 0, stream>>>(acc, src, dst, convb, W1, b1, W2, b2, fcw, fcb, G);
    k_scale<<<(NOUT4 + 255) / 256, 256, 0, stream>>>(Bfon, G, out);
}

// Round 2
// 57.730 us; speedup vs baseline: 1.1108x; 1.1108x over previous
//
#include <hip/hip_runtime.h>

#define NN 16
constexpr int BB = 32, CIN = 64, HH = 112, WW = 112;
constexpr int HWC = HH * WW;          // 12544
constexpr int COUT = 128, HW2 = 56 * 56;
constexpr int NE = 64;
constexpr int NQ = HWC / 4;           // 3136 float4 pixels per image
constexpr int BPI = 13;               // conv blocks per image (13*256 >= 3136)
constexpr int PF4 = COUT * HW2 / 4;   // 100352 float4 per batch plane-set
constexpr int SBPB = 25;              // scale blocks per batch

// ---------------- Kernel 1: 1x1 conv over 64 ch + segment scatter ----------
// Writes per-block partial sums (no global atomics, no memset needed).
__global__ __launch_bounds__(256) void k_conv_seg(
    const float* __restrict__ Bfor, const int* __restrict__ seg,
    const float* __restrict__ convw, float* __restrict__ part)
{
    __shared__ float w[CIN];
    __shared__ float acc[8][NN][4];   // 8-way replicated to cut LDS atomic contention
    const int tid = threadIdx.x;
    const int b   = blockIdx.x / BPI;
    const int blk = blockIdx.x % BPI;

    if (tid < CIN) w[tid] = convw[tid];
    for (int i = tid; i < 8 * NN * 4; i += 256) ((float*)acc)[i] = 0.f;
    __syncthreads();

    const float* base = Bfor + (size_t)b * CIN * HWC;
    const int*   segb = seg  + (size_t)b * HWC;
    const int bank = tid & 7;

    for (int q = blk * 256 + tid; q < NQ; q += BPI * 256) {
        const int p = q * 4;
        float4 s = make_float4(0.f, 0.f, 0.f, 0.f);
        #pragma unroll 8
        for (int c = 0; c < CIN; ++c) {
            float4 v = *reinterpret_cast<const float4*>(base + (size_t)c * HWC + p);
            const float wc = w[c];
            s.x = fmaf(v.x, wc, s.x);
            s.y = fmaf(v.y, wc, s.y);
            s.z = fmaf(v.z, wc, s.z);
            s.w = fmaf(v.w, wc, s.w);
        }
        const int4 sg = *reinterpret_cast<const int4*>(segb + p);
        const float row  = (float)(p / WW);
        const float col0 = (float)(p % WW);
        atomicAdd(&acc[bank][sg.x][0], row);
        atomicAdd(&acc[bank][sg.x][1], col0);
        atomicAdd(&acc[bank][sg.x][2], s.x);
        atomicAdd(&acc[bank][sg.x][3], 1.f);
        atomicAdd(&acc[bank][sg.y][0], row);
        atomicAdd(&acc[bank][sg.y][1], col0 + 1.f);
        atomicAdd(&acc[bank][sg.y][2], s.y);
        atomicAdd(&acc[bank][sg.y][3], 1.f);
        atomicAdd(&acc[bank][sg.z][0], row);
        atomicAdd(&acc[bank][sg.z][1], col0 + 2.f);
        atomicAdd(&acc[bank][sg.z][2], s.z);
        atomicAdd(&acc[bank][sg.z][3], 1.f);
        atomicAdd(&acc[bank][sg.w][0], row);
        atomicAdd(&acc[bank][sg.w][1], col0 + 3.f);
        atomicAdd(&acc[bank][sg.w][2], s.w);
        atomicAdd(&acc[bank][sg.w][3], 1.f);
    }
    __syncthreads();

    if (tid < NN * 4) {
        const int node = tid >> 2, st = tid & 3;
        float v = 0.f;
        #pragma unroll
        for (int k = 0; k < 8; ++k) v += acc[k][node][st];
        part[((b * BPI + blk) * NN + node) * 4 + st] = v;
    }
}

// ------- Kernel 2: fused graph stage (redundant per block) + broadcast scale
__global__ __launch_bounds__(256) void k_graph_scale(
    const float* __restrict__ part, const int* __restrict__ src,
    const int* __restrict__ dst,  const float* __restrict__ convb,
    const float* __restrict__ W1, const float* __restrict__ b1,
    const float* __restrict__ W2, const float* __restrict__ b2,
    const float* __restrict__ fcw, const float* __restrict__ fcb,
    const float* __restrict__ Bfon, float* __restrict__ out)
{
    const int b    = blockIdx.x / SBPB;
    const int blkb = blockIdx.x % SBPB;
    const int tid  = threadIdx.x;

    __shared__ float X[NN][4];
    __shared__ float A[NN][NN];
    __shared__ float nrm[NN];
    __shared__ float h1s[NN][32];
    __shared__ float agg[NN][32];
    __shared__ float Gs[COUT];

    // ---- Phase A: tiny graph network (redundant across SBPB blocks) ----
    if (tid < NN * 4) {   // reduce 13 conv-block partials
        const int node = tid >> 2, st = tid & 3;
        float v = 0.f;
        #pragma unroll
        for (int k = 0; k < BPI; ++k) v += part[((b * BPI + k) * NN + node) * 4 + st];
        ((float*)X)[tid] = v;
    }
    for (int i = tid; i < NN * NN; i += 256) ((float*)A)[i] = 0.f;
    __syncthreads();

    if (tid < NN) {       // raw sums -> features (conv bias folded in)
        const float cnt = X[tid][3];
        const float cs  = fmaxf(cnt, 1.f);
        X[tid][0] = X[tid][0] / cs;
        X[tid][1] = X[tid][1] / cs;
        X[tid][2] = (X[tid][2] + cnt * convb[0]) / cs;
    }
    __syncthreads();

    // normalize feature cols 2,3 across nodes (mean, std ddof=1)
    if (tid < 2) {
        const int c = 2 + tid;
        float mu = 0.f;
        for (int i = 0; i < NN; ++i) mu += X[i][c];
        mu *= (1.f / NN);
        float var = 0.f;
        for (int i = 0; i < NN; ++i) { const float d = X[i][c] - mu; var = fmaf(d, d, var); }
        var *= (1.f / (NN - 1));
        const float inv = 1.f / (sqrtf(var) + 1.f);
        for (int i = 0; i < NN; ++i) X[i][c] = (X[i][c] - mu) * inv;
    }
    // build adjacency (idempotent set-to-1)
    if (tid >= 64 && tid < 64 + NE) {
        const int e = tid - 64;
        const int s = src[b * NE + e], d = dst[b * NE + e];
        A[s][d] = 1.f;
        A[d][s] = 1.f;
    }
    __syncthreads();

    if (tid < NN) {
        float rs = 0.f;
        for (int j = 0; j < NN; ++j) rs += A[tid][j];
        nrm[tid] = 1.f / sqrtf(fmaxf(rs, 1.f));
    }
    __syncthreads();

    if (tid < NN * 4) {   // agg1 (16x4)
        const int i = tid >> 2, k = tid & 3;
        float s = 0.f;
        for (int j = 0; j < NN; ++j) s = fmaf(A[i][j] * nrm[j], X[j][k], s);
        agg[i][k] = s;
    }
    __syncthreads();

    for (int t = tid; t < NN * 32; t += 256) {   // h1 (16x32)
        const int i = t >> 5, f = t & 31;
        float s = 0.f;
        #pragma unroll
        for (int k = 0; k < 4; ++k) s = fmaf(agg[i][k], W1[k * 32 + f], s);
        h1s[i][f] = fmaxf(fmaf(nrm[i], s, b1[f]), 0.f);
    }
    __syncthreads();

    for (int t = tid; t < NN * 32; t += 256) {   // agg2 (16x32)
        const int i = t >> 5, k = t & 31;
        float s = 0.f;
        for (int j = 0; j < NN; ++j) s = fmaf(A[i][j] * nrm[j], h1s[j][k], s);
        agg[i][k] = s;
    }
    __syncthreads();

    if (tid < COUT) {     // h2 + FC -> Gs[128]
        const int f = tid;
        float g = fcb[0];
        const float bf = b2[f];
        for (int i = 0; i < NN; ++i) {
            float s = 0.f;
            #pragma unroll 8
            for (int k = 0; k < 32; ++k) s = fmaf(agg[i][k], W2[k * COUT + f], s);
            const float h2 = fmaxf(fmaf(nrm[i], s, bf), 0.f);
            g = fmaf(fcw[i], h2, g);
        }
        Gs[f] = g;
    }
    __syncthreads();

    // ---- Phase B: out[b,c,:,:] = Gs[c] * B_fon[b,c,:,:] (this block's slice)
    const float4* bf4 = reinterpret_cast<const float4*>(Bfon) + (size_t)b * PF4;
    float4*       ob4 = reinterpret_cast<float4*>(out)        + (size_t)b * PF4;
    for (int t = blkb * 256 + tid; t < PF4; t += SBPB * 256) {
        const float4 v = bf4[t];
        const float  g = Gs[t / (HW2 / 4)];   // 784 float4s per (b,c) plane
        ob4[t] = make_float4(v.x * g, v.y * g, v.z * g, v.w * g);
    }
}

extern "C" void kernel_launch(void* const* d_in, const int* in_sizes, int n_in,
                              void* d_out, int out_size, void* d_ws, size_t ws_size,
                              hipStream_t stream)
{
    const float* Bfor  = (const float*)d_in[0];
    const float* Bfon  = (const float*)d_in[1];
    const int*   seg   = (const int*)d_in[2];
    const int*   src   = (const int*)d_in[3];
    const int*   dst   = (const int*)d_in[4];
    const float* convw = (const float*)d_in[5];
    const float* convb = (const float*)d_in[6];
    const float* W1    = (const float*)d_in[7];
    const float* b1    = (const float*)d_in[8];
    const float* W2    = (const float*)d_in[9];
    const float* b2    = (const float*)d_in[10];
    const float* fcw   = (const float*)d_in[11];
    const float* fcb   = (const float*)d_in[12];

    float* part = (float*)d_ws;           // BB*BPI*NN*4 floats = 106 KB
    float* out  = (float*)d_out;

    k_conv_seg<<<BB * BPI, 256, 0, stream>>>(Bfor, seg, convw, part);
    k_graph_scale<<<BB * SBPB, 256, 0, stream>>>(part, src, dst, convb,
                                                 W1, b1, W2, b2, fcw, fcb,
                                                 Bfon, out);
}

// Round 3
// 48.837 us; speedup vs baseline: 1.3131x; 1.1821x over previous
//
#include <hip/hip_runtime.h>

#define NN 16
constexpr int BB = 32, CIN = 64, HH = 112, WW = 112;
constexpr int HWC = HH * WW;          // 12544
constexpr int COUT = 128, HW2 = 56 * 56;
constexpr int NE = 64;
constexpr int NQ = HWC / 4;           // 3136 float4 pixels per image
constexpr int QPB = 64;               // pixel-quads per conv block
constexpr int BPI = NQ / QPB;         // 49 conv blocks per image (exact)
constexpr int PF4 = COUT * HW2 / 4;   // 100352 float4 per batch
constexpr int SBPB = 25;              // scale blocks per batch

// ---------------- Kernel 1: 1x1 conv (channel-split) + segment scatter -----
// 256 threads = 64 pixel-quads x 4 channel-groups. Each thread reduces 16
// channels; LDS combine; wave 0 does the skewed-bank LDS atomic scatter.
__global__ __launch_bounds__(256) void k_conv_seg(
    const float* __restrict__ Bfor, const int* __restrict__ seg,
    const float* __restrict__ convw, float* __restrict__ part)
{
    __shared__ float w[CIN];
    __shared__ float ps[4 * QPB * 5];   // [cg][quad][px], px stride 5 (bank skew)
    __shared__ float acc[8 * 80];       // [replica][node*5+st], skewed banks
    const int tid = threadIdx.x;
    const int b   = blockIdx.x / BPI;
    const int blk = blockIdx.x % BPI;
    const int cg  = tid >> 6;           // channel group == wave id
    const int l   = tid & 63;           // quad lane

    if (tid < CIN) w[tid] = convw[tid];
    for (int i = tid; i < 8 * 80; i += 256) acc[i] = 0.f;
    __syncthreads();

    const int q = blk * QPB + l;        // < 3136 always (exact tiling)
    const int p = q * 4;
    const float* base = Bfor + (size_t)b * CIN * HWC + (size_t)(cg * 16) * HWC + p;

    float4 s = make_float4(0.f, 0.f, 0.f, 0.f);
    #pragma unroll
    for (int cc = 0; cc < 16; ++cc) {
        const float4 v = *reinterpret_cast<const float4*>(base + (size_t)cc * HWC);
        const float wc = w[cg * 16 + cc];
        s.x = fmaf(v.x, wc, s.x);
        s.y = fmaf(v.y, wc, s.y);
        s.z = fmaf(v.z, wc, s.z);
        s.w = fmaf(v.w, wc, s.w);
    }
    ps[cg * 320 + l * 5 + 0] = s.x;
    ps[cg * 320 + l * 5 + 1] = s.y;
    ps[cg * 320 + l * 5 + 2] = s.z;
    ps[cg * 320 + l * 5 + 3] = s.w;
    __syncthreads();

    if (tid < 64) {
        float r0 = 0.f, r1 = 0.f, r2 = 0.f, r3 = 0.f;
        #pragma unroll
        for (int g = 0; g < 4; ++g) {
            r0 += ps[g * 320 + tid * 5 + 0];
            r1 += ps[g * 320 + tid * 5 + 1];
            r2 += ps[g * 320 + tid * 5 + 2];
            r3 += ps[g * 320 + tid * 5 + 3];
        }
        const int pp = (blk * QPB + tid) * 4;
        const int4 sg = *reinterpret_cast<const int4*>(seg + (size_t)b * HWC + pp);
        const float row  = (float)(pp / WW);   // WW%4==0 -> all 4 px same row
        const float col0 = (float)(pp % WW);
        const int k = tid & 7;                 // replica
        atomicAdd(&acc[k * 80 + sg.x * 5 + 0], row);
        atomicAdd(&acc[k * 80 + sg.x * 5 + 1], col0);
        atomicAdd(&acc[k * 80 + sg.x * 5 + 2], r0);
        atomicAdd(&acc[k * 80 + sg.x * 5 + 3], 1.f);
        atomicAdd(&acc[k * 80 + sg.y * 5 + 0], row);
        atomicAdd(&acc[k * 80 + sg.y * 5 + 1], col0 + 1.f);
        atomicAdd(&acc[k * 80 + sg.y * 5 + 2], r1);
        atomicAdd(&acc[k * 80 + sg.y * 5 + 3], 1.f);
        atomicAdd(&acc[k * 80 + sg.z * 5 + 0], row);
        atomicAdd(&acc[k * 80 + sg.z * 5 + 1], col0 + 2.f);
        atomicAdd(&acc[k * 80 + sg.z * 5 + 2], r2);
        atomicAdd(&acc[k * 80 + sg.z * 5 + 3], 1.f);
        atomicAdd(&acc[k * 80 + sg.w * 5 + 0], row);
        atomicAdd(&acc[k * 80 + sg.w * 5 + 1], col0 + 3.f);
        atomicAdd(&acc[k * 80 + sg.w * 5 + 2], r3);
        atomicAdd(&acc[k * 80 + sg.w * 5 + 3], 1.f);
    }
    __syncthreads();

    if (tid < NN * 4) {
        const int node = tid >> 2, st = tid & 3;
        float v = 0.f;
        #pragma unroll
        for (int k = 0; k < 8; ++k) v += acc[k * 80 + node * 5 + st];
        part[((b * BPI + blk) * NN + node) * 4 + st] = v;
    }
}

// ------- Kernel 2: fused graph stage (redundant per block) + broadcast scale
__global__ __launch_bounds__(256) void k_graph_scale(
    const float* __restrict__ part, const int* __restrict__ src,
    const int* __restrict__ dst,  const float* __restrict__ convb,
    const float* __restrict__ W1, const float* __restrict__ b1,
    const float* __restrict__ W2, const float* __restrict__ b2,
    const float* __restrict__ fcw, const float* __restrict__ fcb,
    const float* __restrict__ Bfon, float* __restrict__ out)
{
    const int b    = blockIdx.x / SBPB;
    const int blkb = blockIdx.x % SBPB;
    const int tid  = threadIdx.x;

    __shared__ float X[NN][4];
    __shared__ float A[NN][NN];
    __shared__ float nrm[NN];
    __shared__ float h1s[NN][32];
    __shared__ float agg[NN][32];
    __shared__ float gpart[2][COUT];
    __shared__ float Gs[COUT];

    // ---- Phase A: tiny graph network (redundant across SBPB blocks) ----
    if (tid < 64) {        // reduce 49 conv-block partials; coalesced per iter
        const int node = tid >> 2, st = tid & 3;
        float v = 0.f;
        for (int k = 0; k < BPI; ++k) v += part[((b * BPI + k) * NN + node) * 4 + st];
        X[node][st] = v;
    }
    for (int i = tid; i < NN * NN; i += 256) ((float*)A)[i] = 0.f;
    __syncthreads();

    if (tid < NN) {        // raw sums -> features (conv bias folded in)
        const float cnt = X[tid][3];
        const float cs  = fmaxf(cnt, 1.f);
        X[tid][0] = X[tid][0] / cs;
        X[tid][1] = X[tid][1] / cs;
        X[tid][2] = (X[tid][2] + cnt * convb[0]) / cs;
    }
    __syncthreads();

    // normalize feature cols 2,3 across nodes (mean, std ddof=1)
    if (tid < 2) {
        const int c = 2 + tid;
        float mu = 0.f;
        for (int i = 0; i < NN; ++i) mu += X[i][c];
        mu *= (1.f / NN);
        float var = 0.f;
        for (int i = 0; i < NN; ++i) { const float d = X[i][c] - mu; var = fmaf(d, d, var); }
        var *= (1.f / (NN - 1));
        const float inv = 1.f / (sqrtf(var) + 1.f);
        for (int i = 0; i < NN; ++i) X[i][c] = (X[i][c] - mu) * inv;
    }
    // build adjacency (idempotent set-to-1)
    if (tid >= 64 && tid < 64 + NE) {
        const int e = tid - 64;
        const int s = src[b * NE + e], d = dst[b * NE + e];
        A[s][d] = 1.f;
        A[d][s] = 1.f;
    }
    __syncthreads();

    if (tid < NN) {
        float rs = 0.f;
        for (int j = 0; j < NN; ++j) rs += A[tid][j];
        nrm[tid] = 1.f / sqrtf(fmaxf(rs, 1.f));
    }
    __syncthreads();

    if (tid < NN * 4) {    // agg1 (16x4)
        const int i = tid >> 2, k = tid & 3;
        float s = 0.f;
        for (int j = 0; j < NN; ++j) s = fmaf(A[i][j] * nrm[j], X[j][k], s);
        agg[i][k] = s;
    }
    __syncthreads();

    for (int t = tid; t < NN * 32; t += 256) {   // h1 (16x32)
        const int i = t >> 5, f = t & 31;
        float s = 0.f;
        #pragma unroll
        for (int k = 0; k < 4; ++k) s = fmaf(agg[i][k], W1[k * 32 + f], s);
        h1s[i][f] = fmaxf(fmaf(nrm[i], s, b1[f]), 0.f);
    }
    __syncthreads();

    for (int t = tid; t < NN * 32; t += 256) {   // agg2 (16x32)
        const int i = t >> 5, k = t & 31;
        float s = 0.f;
        for (int j = 0; j < NN; ++j) s = fmaf(A[i][j] * nrm[j], h1s[j][k], s);
        agg[i][k] = s;
    }
    __syncthreads();

    {   // h2 + FC, i-range split across 2 half-blocks (256-FMA chain each)
        const int f = tid & 127, half = tid >> 7;
        float g = 0.f;
        const float bf = b2[f];
        for (int i = half * 8; i < half * 8 + 8; ++i) {
            float s = 0.f;
            #pragma unroll
            for (int k = 0; k < 32; ++k) s = fmaf(agg[i][k], W2[k * COUT + f], s);
            g = fmaf(fcw[i], fmaxf(fmaf(nrm[i], s, bf), 0.f), g);
        }
        gpart[half][f] = g;
    }
    __syncthreads();
    if (tid < COUT) Gs[tid] = gpart[0][tid] + gpart[1][tid] + fcb[0];
    __syncthreads();

    // ---- Phase B: out[b,c,:,:] = Gs[c] * B_fon[b,c,:,:] (this block's slice)
    const float4* bf4 = reinterpret_cast<const float4*>(Bfon) + (size_t)b * PF4;
    float4*       ob4 = reinterpret_cast<float4*>(out)        + (size_t)b * PF4;
    for (int t = blkb * 256 + tid; t < PF4; t += SBPB * 256) {
        const float4 v = bf4[t];
        const float  g = Gs[t / (HW2 / 4)];   // 784 float4s per (b,c) plane
        ob4[t] = make_float4(v.x * g, v.y * g, v.z * g, v.w * g);
    }
}

extern "C" void kernel_launch(void* const* d_in, const int* in_sizes, int n_in,
                              void* d_out, int out_size, void* d_ws, size_t ws_size,
                              hipStream_t stream)
{
    const float* Bfor  = (const float*)d_in[0];
    const float* Bfon  = (const float*)d_in[1];
    const int*   seg   = (const int*)d_in[2];
    const int*   src   = (const int*)d_in[3];
    const int*   dst   = (const int*)d_in[4];
    const float* convw = (const float*)d_in[5];
    const float* convb = (const float*)d_in[6];
    const float* W1    = (const float*)d_in[7];
    const float* b1    = (const float*)d_in[8];
    const float* W2    = (const float*)d_in[9];
    const float* b2    = (const float*)d_in[10];
    const float* fcw   = (const float*)d_in[11];
    const float* fcb   = (const float*)d_in[12];

    float* part = (float*)d_ws;           // BB*BPI*NN*4 floats = 401 KB
    float* out  = (float*)d_out;

    k_conv_seg<<<BB * BPI, 256, 0, stream>>>(Bfor, seg, convw, part);
    k_graph_scale<<<BB * SBPB, 256, 0, stream>>>(part, src, dst, convb,
                                                 W1, b1, W2, b2, fcw, fcb,
                                                 Bfon, out);
}